// Round 1
// baseline (408.369 us; speedup 1.0000x reference)
//
#include <hip/hip_runtime.h>

#define B_   4
#define N1_  8192
#define N2_  2048
#define CIN  512
#define COUT 256

typedef __attribute__((ext_vector_type(8))) short bf16x8;
typedef __attribute__((ext_vector_type(4))) float f32x4;

__device__ inline short f2bf(float f) {
  union { float f; unsigned u; } v; v.f = f;
  unsigned r = v.u + 0x7fffu + ((v.u >> 16) & 1u);
  return (short)(r >> 16);
}

__device__ inline float relu_(float x) { return fmaxf(x, 0.0f); }

// ---------------------------------------------------------------------------
// GEMM: Y[M][256] = X[M][K] @ W[K][256] + bias, computed in bf16 MFMA, fp32 acc
// Tile: BM=64, BN=64, BK=32. 256 threads = 4 waves in 2x2, each wave 32x32.
// ---------------------------------------------------------------------------
#define BM 64
#define BN 64
#define BK 32

__global__ __launch_bounds__(256) void gemm_bias(
    const float* __restrict__ X, const float* __restrict__ W,
    const float* __restrict__ bias, float* __restrict__ Y,
    int M, int K)
{
  const int N = 256;
  __shared__ __align__(16) short As[BM][BK + 8];   // pad 8 shorts = 16B -> stride 80B
  __shared__ __align__(16) short Bs[BN][BK + 8];   // stores W^T tile: Bs[n][k]

  const int bm = blockIdx.x * BM;
  const int bn = blockIdx.y * BN;
  const int tid = threadIdx.x;
  const int lane = tid & 63;
  const int wave = tid >> 6;          // 0..3
  const int wm = (wave & 1) * 32;     // wave row offset within tile
  const int wn = (wave >> 1) * 32;    // wave col offset within tile

  f32x4 acc[2][2];
  for (int i = 0; i < 2; i++)
    for (int j = 0; j < 2; j++)
      for (int e = 0; e < 4; e++) acc[i][j][e] = 0.0f;

  const int a_k = tid & 31;        // 0..31
  const int a_m0 = tid >> 5;       // 0..7
  const int b_n = tid & 63;        // 0..63
  const int b_k0 = tid >> 6;       // 0..3

  for (int k0 = 0; k0 < K; k0 += BK) {
    // stage A tile (64 x 32): coalesced global fp32 reads, convert to bf16
    for (int mm = a_m0; mm < BM; mm += 8) {
      float v = X[(size_t)(bm + mm) * K + (k0 + a_k)];
      As[mm][a_k] = f2bf(v);
    }
    // stage B tile (32 x 64) transposed into Bs[n][k]
    for (int kk = b_k0; kk < BK; kk += 4) {
      float v = W[(size_t)(k0 + kk) * N + (bn + b_n)];
      Bs[b_n][kk] = f2bf(v);
    }
    __syncthreads();

    // fragments: A[m=lane&15][k=(lane>>4)*8+j]; B via transposed tile same form
    const int fr = lane & 15;
    const int kq = (lane >> 4) * 8;
    bf16x8 a0 = *(const bf16x8*)&As[wm + fr][kq];
    bf16x8 a1 = *(const bf16x8*)&As[wm + 16 + fr][kq];
    bf16x8 b0 = *(const bf16x8*)&Bs[wn + fr][kq];
    bf16x8 b1 = *(const bf16x8*)&Bs[wn + 16 + fr][kq];

    acc[0][0] = __builtin_amdgcn_mfma_f32_16x16x32_bf16(a0, b0, acc[0][0], 0, 0, 0);
    acc[0][1] = __builtin_amdgcn_mfma_f32_16x16x32_bf16(a0, b1, acc[0][1], 0, 0, 0);
    acc[1][0] = __builtin_amdgcn_mfma_f32_16x16x32_bf16(a1, b0, acc[1][0], 0, 0, 0);
    acc[1][1] = __builtin_amdgcn_mfma_f32_16x16x32_bf16(a1, b1, acc[1][1], 0, 0, 0);
    __syncthreads();
  }

  // C/D layout: col = lane&15, row = (lane>>4)*4 + reg
  const int col = lane & 15;
  const int rq = (lane >> 4) * 4;
  for (int mi = 0; mi < 2; mi++) {
    for (int ni = 0; ni < 2; ni++) {
      const int gm = bm + wm + mi * 16 + rq;
      const int gn = bn + wn + ni * 16 + col;
      const float bb = bias[gn];
      for (int j = 0; j < 4; j++) {
        Y[(size_t)(gm + j) * N + gn] = acc[mi][ni][j] + bb;
      }
    }
  }
}

// ---------------------------------------------------------------------------
// Per-channel sum / sumsq over rows of Y[M][256]
// ---------------------------------------------------------------------------
__global__ __launch_bounds__(256) void col_stats(
    const float* __restrict__ Y, float* __restrict__ sums, int M)
{
  const int c = threadIdx.x;   // channel 0..255
  float s = 0.0f, s2 = 0.0f;
  for (int m = blockIdx.x; m < M; m += gridDim.x) {
    float v = Y[(size_t)m * 256 + c];
    s += v;
    s2 += v * v;
  }
  atomicAdd(&sums[c], s);
  atomicAdd(&sums[256 + c], s2);
}

__global__ __launch_bounds__(256) void finalize_stats(
    const float* __restrict__ sums, const float* __restrict__ gamma,
    const float* __restrict__ beta, float* __restrict__ ss, float invM)
{
  const int c = threadIdx.x;
  float mean = sums[c] * invM;
  float var = sums[256 + c] * invM - mean * mean;   // biased var, matches jnp.var
  float sc = gamma[c] * rsqrtf(var + 1e-5f);
  ss[c] = sc;
  ss[256 + c] = beta[c] - mean * sc;
}

// ---------------------------------------------------------------------------
// 3-NN of each p1 point among the 2048 p2 points (per batch); IDW weights.
// ---------------------------------------------------------------------------
__global__ __launch_bounds__(128) void knn_weights(
    const float* __restrict__ p1, const float* __restrict__ p2,
    float* __restrict__ wgt, int* __restrict__ idx)
{
  __shared__ float4 sp2[N2_];   // 32 KB: x,y,z,|p|^2
  const int b = blockIdx.y;
  const float* P2 = p2 + (size_t)b * N2_ * 3;
  for (int j = threadIdx.x; j < N2_; j += blockDim.x) {
    float x = P2[j * 3 + 0], y = P2[j * 3 + 1], z = P2[j * 3 + 2];
    sp2[j] = make_float4(x, y, z, x * x + y * y + z * z);
  }
  __syncthreads();

  const int n1 = blockIdx.x * blockDim.x + threadIdx.x;
  const float* P1 = p1 + ((size_t)b * N1_ + n1) * 3;
  const float x = P1[0], y = P1[1], z = P1[2];
  const float s1 = x * x + y * y + z * z;
  const float nx = -2.0f * x, ny = -2.0f * y, nz = -2.0f * z;

  float d0 = 1e30f, d1 = 1e30f, d2 = 1e30f;
  int i0 = 0, i1 = 0, i2 = 0;
  for (int j = 0; j < N2_; j++) {
    float4 q = sp2[j];                    // broadcast read (all lanes same addr)
    float d = s1 + q.w + (nx * q.x + ny * q.y + nz * q.z);
    bool lt0 = d < d0, lt1 = d < d1, lt2 = d < d2;
    d2 = lt1 ? d1 : (lt2 ? d : d2);  i2 = lt1 ? i1 : (lt2 ? j : i2);
    d1 = lt0 ? d0 : (lt1 ? d : d1);  i1 = lt0 ? i0 : (lt1 ? j : i1);
    d0 = lt0 ? d  : d0;              i0 = lt0 ? j  : i0;
  }

  float r0 = 1.0f / (d0 + 1e-8f);
  float r1 = 1.0f / (d1 + 1e-8f);
  float r2 = 1.0f / (d2 + 1e-8f);
  float rs = 1.0f / (r0 + r1 + r2);
  size_t o = ((size_t)b * N1_ + n1) * 3;
  wgt[o + 0] = r0 * rs; wgt[o + 1] = r1 * rs; wgt[o + 2] = r2 * rs;
  idx[o + 0] = i0;      idx[o + 1] = i1;      idx[o + 2] = i2;
}

// ---------------------------------------------------------------------------
// Final: out = sum_k w_k * relu(bn2(y2[idx_k])) + relu(bn1(y1))
// One wave per output row; float4 per lane covers 256 channels.
// ---------------------------------------------------------------------------
__global__ __launch_bounds__(256) void final_out(
    const float* __restrict__ y1, const float* __restrict__ y2,
    const float* __restrict__ ss1, const float* __restrict__ ss2,
    const float* __restrict__ wgt, const int* __restrict__ idx,
    float* __restrict__ out)
{
  const int r = blockIdx.x * 4 + (threadIdx.x >> 6);   // global row 0..32767
  const int lane = threadIdx.x & 63;
  const int b = r >> 13;                               // / 8192
  const size_t wo = (size_t)r * 3;
  const float w0 = wgt[wo], w1 = wgt[wo + 1], w2 = wgt[wo + 2];
  const int i0 = idx[wo], i1 = idx[wo + 1], i2 = idx[wo + 2];

  const float* g0 = y2 + ((size_t)b * N2_ + i0) * 256;
  const float* g1 = y2 + ((size_t)b * N2_ + i1) * 256;
  const float* g2 = y2 + ((size_t)b * N2_ + i2) * 256;
  const int c = lane * 4;

  float4 f0 = *(const float4*)&g0[c];
  float4 f1 = *(const float4*)&g1[c];
  float4 f2 = *(const float4*)&g2[c];
  float4 v1 = *(const float4*)&y1[(size_t)r * 256 + c];
  float4 sc2 = *(const float4*)&ss2[c];
  float4 sh2 = *(const float4*)&ss2[256 + c];
  float4 sc1 = *(const float4*)&ss1[c];
  float4 sh1 = *(const float4*)&ss1[256 + c];

  float4 o;
  o.x = w0 * relu_(f0.x * sc2.x + sh2.x) + w1 * relu_(f1.x * sc2.x + sh2.x)
      + w2 * relu_(f2.x * sc2.x + sh2.x) + relu_(v1.x * sc1.x + sh1.x);
  o.y = w0 * relu_(f0.y * sc2.y + sh2.y) + w1 * relu_(f1.y * sc2.y + sh2.y)
      + w2 * relu_(f2.y * sc2.y + sh2.y) + relu_(v1.y * sc1.y + sh1.y);
  o.z = w0 * relu_(f0.z * sc2.z + sh2.z) + w1 * relu_(f1.z * sc2.z + sh2.z)
      + w2 * relu_(f2.z * sc2.z + sh2.z) + relu_(v1.z * sc1.z + sh1.z);
  o.w = w0 * relu_(f0.w * sc2.w + sh2.w) + w1 * relu_(f1.w * sc2.w + sh2.w)
      + w2 * relu_(f2.w * sc2.w + sh2.w) + relu_(v1.w * sc1.w + sh1.w);

  *(float4*)&out[(size_t)r * 256 + c] = o;
}

// ---------------------------------------------------------------------------
extern "C" void kernel_launch(void* const* d_in, const int* in_sizes, int n_in,
                              void* d_out, int out_size, void* d_ws, size_t ws_size,
                              hipStream_t stream)
{
  const float* p1  = (const float*)d_in[0];
  const float* x1  = (const float*)d_in[1];
  const float* p2  = (const float*)d_in[2];
  const float* x2  = (const float*)d_in[3];
  const float* W1  = (const float*)d_in[4];
  const float* b1  = (const float*)d_in[5];
  const float* g1  = (const float*)d_in[6];
  const float* be1 = (const float*)d_in[7];
  const float* W2  = (const float*)d_in[8];
  const float* b2  = (const float*)d_in[9];
  const float* g2  = (const float*)d_in[10];
  const float* be2 = (const float*)d_in[11];
  float* out = (float*)d_out;
  char* ws = (char*)d_ws;

  // workspace layout (bytes)
  float* y1    = (float*)(ws + 0);            // 32768*256*4 = 33554432
  float* y2    = (float*)(ws + 33554432);     // 8192*256*4  =  8388608
  float* stats = (float*)(ws + 41943040);     // 1024 floats (y1: 0..511, y2: 512..1023)
  float* ss    = (float*)(ws + 41947136);     // 1024 floats (ss1: 0..511, ss2: 512..1023)
  float* wgt   = (float*)(ws + 41951232);     // 32768*3 floats
  int*   idx   = (int*)  (ws + 42344448);     // 32768*3 ints

  hipMemsetAsync(stats, 0, 4096, stream);

  gemm_bias<<<dim3((B_ * N2_) / BM, COUT / BN), 256, 0, stream>>>(x2, W2, b2, y2, B_ * N2_, CIN);
  gemm_bias<<<dim3((B_ * N1_) / BM, COUT / BN), 256, 0, stream>>>(x1, W1, b1, y1, B_ * N1_, COUT);

  col_stats<<<256, 256, 0, stream>>>(y1, stats, B_ * N1_);
  col_stats<<<256, 256, 0, stream>>>(y2, stats + 512, B_ * N2_);

  finalize_stats<<<1, 256, 0, stream>>>(stats,       g1, be1, ss,       1.0f / (B_ * N1_));
  finalize_stats<<<1, 256, 0, stream>>>(stats + 512, g2, be2, ss + 512, 1.0f / (B_ * N2_));

  knn_weights<<<dim3(N1_ / 128, B_), 128, 0, stream>>>(p1, p2, wgt, idx);

  final_out<<<(B_ * N1_) / 4, 256, 0, stream>>>(y1, y2, ss, ss + 512, wgt, idx, out);
}

// Round 2
// 264.508 us; speedup vs baseline: 1.5439x; 1.5439x over previous
//
#include <hip/hip_runtime.h>

#define B_   4
#define N1_  8192
#define N2_  2048
#define CIN  512
#define COUT 256

typedef __attribute__((ext_vector_type(8))) short bf16x8;
typedef __attribute__((ext_vector_type(4))) float f32x4;

__device__ inline short f2bf(float f) {
  union { float f; unsigned u; } v; v.f = f;
  unsigned r = v.u + 0x7fffu + ((v.u >> 16) & 1u);
  return (short)(r >> 16);
}
__device__ inline float bf2f(short s) {
  union { unsigned u; float f; } v; v.u = ((unsigned)(unsigned short)s) << 16;
  return v.f;
}
__device__ inline float relu_(float x) { return fmaxf(x, 0.0f); }

// ---------------------------------------------------------------------------
// W [K][256] fp32  ->  Wt [256][K] bf16   (one-time, tiny)
// ---------------------------------------------------------------------------
__global__ __launch_bounds__(256) void cvt_wt(
    const float* __restrict__ W, short* __restrict__ Wt, int K)
{
  int i = blockIdx.x * 256 + threadIdx.x;   // over K*256, coalesced read
  int k = i >> 8, n = i & 255;
  Wt[(size_t)n * K + k] = f2bf(W[i]);
}

// ---------------------------------------------------------------------------
// GEMM: Y[M][256](bf16) = X[M][K](fp32) @ Wt^T(bf16) + bias
// Tile BM=64 x BN=128 x BK=64. 256 threads = 4 waves; wave does 32x64.
// ---------------------------------------------------------------------------
#define BM 64
#define BN 128
#define BK 64

__global__ __launch_bounds__(256) void gemm_bias(
    const float* __restrict__ X, const short* __restrict__ Wt,
    const float* __restrict__ bias, short* __restrict__ Y,
    int M, int K)
{
  __shared__ __align__(16) short As[BM][BK + 8];   // 64 x 72 shorts
  __shared__ __align__(16) short Bs[BN][BK + 8];   // 128 x 72 shorts (Wt rows)

  const int bm = blockIdx.x * BM;
  const int bn = blockIdx.y * BN;
  const int tid = threadIdx.x;
  const int lane = tid & 63;
  const int wave = tid >> 6;
  const int wm = (wave & 1) * 32;
  const int wn = (wave >> 1) * 64;

  f32x4 acc[2][4];
  for (int i = 0; i < 2; i++)
    for (int j = 0; j < 4; j++)
      for (int e = 0; e < 4; e++) acc[i][j][e] = 0.0f;

  const int ar = tid >> 4;         // A: 16 threads/row, float4 each
  const int ak = (tid & 15) * 4;
  const int br = tid >> 3;         // B: 8 threads/row, bf16x8 each
  const int bk = (tid & 7) * 8;

  for (int k0 = 0; k0 < K; k0 += BK) {
    #pragma unroll
    for (int r = ar; r < BM; r += 16) {
      float4 v = *(const float4*)&X[(size_t)(bm + r) * K + k0 + ak];
      short4 s = { f2bf(v.x), f2bf(v.y), f2bf(v.z), f2bf(v.w) };
      *(short4*)&As[r][ak] = s;
    }
    #pragma unroll
    for (int r = br; r < BN; r += 32) {
      *(bf16x8*)&Bs[r][bk] = *(const bf16x8*)&Wt[(size_t)(bn + r) * K + k0 + bk];
    }
    __syncthreads();

    const int fr = lane & 15;
    const int kq = (lane >> 4) * 8;
    #pragma unroll
    for (int ks = 0; ks < BK; ks += 32) {
      bf16x8 a0 = *(const bf16x8*)&As[wm + fr][ks + kq];
      bf16x8 a1 = *(const bf16x8*)&As[wm + 16 + fr][ks + kq];
      bf16x8 b0 = *(const bf16x8*)&Bs[wn + fr][ks + kq];
      bf16x8 b1 = *(const bf16x8*)&Bs[wn + 16 + fr][ks + kq];
      bf16x8 b2 = *(const bf16x8*)&Bs[wn + 32 + fr][ks + kq];
      bf16x8 b3 = *(const bf16x8*)&Bs[wn + 48 + fr][ks + kq];
      acc[0][0] = __builtin_amdgcn_mfma_f32_16x16x32_bf16(a0, b0, acc[0][0], 0, 0, 0);
      acc[0][1] = __builtin_amdgcn_mfma_f32_16x16x32_bf16(a0, b1, acc[0][1], 0, 0, 0);
      acc[0][2] = __builtin_amdgcn_mfma_f32_16x16x32_bf16(a0, b2, acc[0][2], 0, 0, 0);
      acc[0][3] = __builtin_amdgcn_mfma_f32_16x16x32_bf16(a0, b3, acc[0][3], 0, 0, 0);
      acc[1][0] = __builtin_amdgcn_mfma_f32_16x16x32_bf16(a1, b0, acc[1][0], 0, 0, 0);
      acc[1][1] = __builtin_amdgcn_mfma_f32_16x16x32_bf16(a1, b1, acc[1][1], 0, 0, 0);
      acc[1][2] = __builtin_amdgcn_mfma_f32_16x16x32_bf16(a1, b2, acc[1][2], 0, 0, 0);
      acc[1][3] = __builtin_amdgcn_mfma_f32_16x16x32_bf16(a1, b3, acc[1][3], 0, 0, 0);
    }
    __syncthreads();
  }

  // C/D: col = lane&15, row = (lane>>4)*4 + j
  const int col = lane & 15;
  const int rq = (lane >> 4) * 4;
  #pragma unroll
  for (int mi = 0; mi < 2; mi++) {
    #pragma unroll
    for (int ni = 0; ni < 4; ni++) {
      const int gm = bm + wm + mi * 16 + rq;
      const int gn = bn + wn + ni * 16 + col;
      const float bb = bias[gn];
      #pragma unroll
      for (int j = 0; j < 4; j++) {
        Y[(size_t)(gm + j) * 256 + gn] = f2bf(acc[mi][ni][j] + bb);
      }
    }
  }
}

// ---------------------------------------------------------------------------
// Per-channel sum / sumsq over rows of Y[M][256] (bf16)
// ---------------------------------------------------------------------------
__global__ __launch_bounds__(256) void col_stats(
    const short* __restrict__ Y, float* __restrict__ sums, int M)
{
  const int c = threadIdx.x;
  float s = 0.0f, s2 = 0.0f;
  for (int m = blockIdx.x; m < M; m += gridDim.x) {
    float v = bf2f(Y[(size_t)m * 256 + c]);
    s += v;
    s2 += v * v;
  }
  atomicAdd(&sums[c], s);
  atomicAdd(&sums[256 + c], s2);
}

__global__ __launch_bounds__(256) void finalize_stats(
    const float* __restrict__ sums, const float* __restrict__ gamma,
    const float* __restrict__ beta, float* __restrict__ ss, float invM)
{
  const int c = threadIdx.x;
  float mean = sums[c] * invM;
  float var = sums[256 + c] * invM - mean * mean;
  float sc = gamma[c] * rsqrtf(var + 1e-5f);
  ss[c] = sc;
  ss[256 + c] = beta[c] - mean * sc;
}

// ---------------------------------------------------------------------------
// 3-NN: 8 threads per query, each scans 256 candidates (stride 8), then
// shfl_xor insert-merge. 256 thr/block = 32 queries/block.
// ---------------------------------------------------------------------------
#define INS(d, j)                                                   \
  { bool lt0 = (d) < d0, lt1 = (d) < d1, lt2 = (d) < d2;            \
    d2 = lt1 ? d1 : (lt2 ? (d) : d2); i2 = lt1 ? i1 : (lt2 ? (j) : i2); \
    d1 = lt0 ? d0 : (lt1 ? (d) : d1); i1 = lt0 ? i0 : (lt1 ? (j) : i1); \
    d0 = lt0 ? (d) : d0;              i0 = lt0 ? (j) : i0; }

__global__ __launch_bounds__(256) void knn_weights(
    const float* __restrict__ p1, const float* __restrict__ p2,
    float* __restrict__ wgt, int* __restrict__ idx)
{
  __shared__ float4 sp2[N2_];   // 32 KB
  const int b = blockIdx.y;
  const float* P2 = p2 + (size_t)b * N2_ * 3;
  for (int j = threadIdx.x; j < N2_; j += 256) {
    float x = P2[j * 3 + 0], y = P2[j * 3 + 1], z = P2[j * 3 + 2];
    sp2[j] = make_float4(x, y, z, x * x + y * y + z * z);
  }
  __syncthreads();

  const int sub = threadIdx.x & 7;
  const int q = blockIdx.x * 32 + (threadIdx.x >> 3);
  const float* P1 = p1 + ((size_t)b * N1_ + q) * 3;
  const float x = P1[0], y = P1[1], z = P1[2];
  const float s1 = x * x + y * y + z * z;
  const float nx = -2.0f * x, ny = -2.0f * y, nz = -2.0f * z;

  float d0 = 1e30f, d1 = 1e30f, d2 = 1e30f;
  int i0 = 0, i1 = 0, i2 = 0;
  #pragma unroll 4
  for (int j = sub; j < N2_; j += 8) {
    float4 qq = sp2[j];
    float d = s1 + qq.w + (nx * qq.x + ny * qq.y + nz * qq.z);
    INS(d, j);
  }

  // merge the 8 partial top-3 lists within each 8-lane group
  #pragma unroll
  for (int m = 1; m < 8; m <<= 1) {
    float e0 = __shfl_xor(d0, m), e1 = __shfl_xor(d1, m), e2 = __shfl_xor(d2, m);
    int j0 = __shfl_xor(i0, m), j1 = __shfl_xor(i1, m), j2 = __shfl_xor(i2, m);
    INS(e0, j0); INS(e1, j1); INS(e2, j2);
  }

  if (sub == 0) {
    float r0 = 1.0f / (d0 + 1e-8f);
    float r1 = 1.0f / (d1 + 1e-8f);
    float r2 = 1.0f / (d2 + 1e-8f);
    float rs = 1.0f / (r0 + r1 + r2);
    size_t o = ((size_t)b * N1_ + q) * 3;
    wgt[o + 0] = r0 * rs; wgt[o + 1] = r1 * rs; wgt[o + 2] = r2 * rs;
    idx[o + 0] = i0;      idx[o + 1] = i1;      idx[o + 2] = i2;
  }
}

// ---------------------------------------------------------------------------
// out = sum_k w_k * relu(bn2(y2[idx_k])) + relu(bn1(y1)); y1/y2 bf16
// One wave per output row; short4 (4 channels) per lane.
// ---------------------------------------------------------------------------
__global__ __launch_bounds__(256) void final_out(
    const short* __restrict__ y1, const short* __restrict__ y2,
    const float* __restrict__ ss1, const float* __restrict__ ss2,
    const float* __restrict__ wgt, const int* __restrict__ idx,
    float* __restrict__ out)
{
  const int r = blockIdx.x * 4 + (threadIdx.x >> 6);
  const int lane = threadIdx.x & 63;
  const int b = r >> 13;
  const size_t wo = (size_t)r * 3;
  const float w0 = wgt[wo], w1 = wgt[wo + 1], w2 = wgt[wo + 2];
  const int i0 = idx[wo], i1 = idx[wo + 1], i2 = idx[wo + 2];

  const short* g0 = y2 + ((size_t)b * N2_ + i0) * 256;
  const short* g1 = y2 + ((size_t)b * N2_ + i1) * 256;
  const short* g2 = y2 + ((size_t)b * N2_ + i2) * 256;
  const int c = lane * 4;

  short4 s0 = *(const short4*)&g0[c];
  short4 s1 = *(const short4*)&g1[c];
  short4 s2 = *(const short4*)&g2[c];
  short4 sv = *(const short4*)&y1[(size_t)r * 256 + c];
  float4 sc2 = *(const float4*)&ss2[c];
  float4 sh2 = *(const float4*)&ss2[256 + c];
  float4 sc1 = *(const float4*)&ss1[c];
  float4 sh1 = *(const float4*)&ss1[256 + c];

  float4 o;
  o.x = w0 * relu_(bf2f(s0.x) * sc2.x + sh2.x) + w1 * relu_(bf2f(s1.x) * sc2.x + sh2.x)
      + w2 * relu_(bf2f(s2.x) * sc2.x + sh2.x) + relu_(bf2f(sv.x) * sc1.x + sh1.x);
  o.y = w0 * relu_(bf2f(s0.y) * sc2.y + sh2.y) + w1 * relu_(bf2f(s1.y) * sc2.y + sh2.y)
      + w2 * relu_(bf2f(s2.y) * sc2.y + sh2.y) + relu_(bf2f(sv.y) * sc1.y + sh1.y);
  o.z = w0 * relu_(bf2f(s0.z) * sc2.z + sh2.z) + w1 * relu_(bf2f(s1.z) * sc2.z + sh2.z)
      + w2 * relu_(bf2f(s2.z) * sc2.z + sh2.z) + relu_(bf2f(sv.z) * sc1.z + sh1.z);
  o.w = w0 * relu_(bf2f(s0.w) * sc2.w + sh2.w) + w1 * relu_(bf2f(s1.w) * sc2.w + sh2.w)
      + w2 * relu_(bf2f(s2.w) * sc2.w + sh2.w) + relu_(bf2f(sv.w) * sc1.w + sh1.w);

  *(float4*)&out[(size_t)r * 256 + c] = o;
}

// ---------------------------------------------------------------------------
extern "C" void kernel_launch(void* const* d_in, const int* in_sizes, int n_in,
                              void* d_out, int out_size, void* d_ws, size_t ws_size,
                              hipStream_t stream)
{
  const float* p1  = (const float*)d_in[0];
  const float* x1  = (const float*)d_in[1];
  const float* p2  = (const float*)d_in[2];
  const float* x2  = (const float*)d_in[3];
  const float* W1  = (const float*)d_in[4];
  const float* b1  = (const float*)d_in[5];
  const float* g1  = (const float*)d_in[6];
  const float* be1 = (const float*)d_in[7];
  const float* W2  = (const float*)d_in[8];
  const float* b2  = (const float*)d_in[9];
  const float* g2  = (const float*)d_in[10];
  const float* be2 = (const float*)d_in[11];
  float* out = (float*)d_out;
  char* ws = (char*)d_ws;

  // workspace layout (bytes), total ~22.2 MB
  short* y1    = (short*)(ws + 0);            // 32768*256*2 = 16777216
  short* y2    = (short*)(ws + 16777216);     // 8192*256*2  =  4194304
  short* Wt1   = (short*)(ws + 20971520);     // 256*256*2   =   131072
  short* Wt2   = (short*)(ws + 21102592);     // 512*256*2   =   262144
  float* stats = (float*)(ws + 21364736);     // 1024 floats
  float* ss    = (float*)(ws + 21368832);     // 1024 floats
  float* wgt   = (float*)(ws + 21372928);     // 32768*3 floats = 393216
  int*   idx   = (int*)  (ws + 21766144);     // 32768*3 ints   = 393216

  hipMemsetAsync(stats, 0, 4096, stream);

  cvt_wt<<<COUT, 256, 0, stream>>>(W1, Wt1, COUT);
  cvt_wt<<<CIN, 256, 0, stream>>>(W2, Wt2, CIN);

  gemm_bias<<<dim3((B_ * N2_) / BM, COUT / BN), 256, 0, stream>>>(x2, Wt2, b2, y2, B_ * N2_, CIN);
  gemm_bias<<<dim3((B_ * N1_) / BM, COUT / BN), 256, 0, stream>>>(x1, Wt1, b1, y1, B_ * N1_, COUT);

  col_stats<<<256, 256, 0, stream>>>(y1, stats, B_ * N1_);
  col_stats<<<256, 256, 0, stream>>>(y2, stats + 512, B_ * N2_);

  finalize_stats<<<1, 256, 0, stream>>>(stats,       g1, be1, ss,       1.0f / (B_ * N1_));
  finalize_stats<<<1, 256, 0, stream>>>(stats + 512, g2, be2, ss + 512, 1.0f / (B_ * N2_));

  knn_weights<<<dim3(N1_ / 32, B_), 256, 0, stream>>>(p1, p2, wgt, idx);

  final_out<<<(B_ * N1_) / 4, 256, 0, stream>>>(y1, y2, ss, ss + 512, wgt, idx, out);
}

// Round 3
// 233.122 us; speedup vs baseline: 1.7517x; 1.1346x over previous
//
#include <hip/hip_runtime.h>

#define B_   4
#define N1_  8192
#define N2_  2048
#define CIN  512
#define COUT 256

typedef __attribute__((ext_vector_type(8))) short bf16x8;
typedef __attribute__((ext_vector_type(4))) float f32x4;

__device__ inline short f2bf(float f) {
  union { float f; unsigned u; } v; v.f = f;
  unsigned r = v.u + 0x7fffu + ((v.u >> 16) & 1u);
  return (short)(r >> 16);
}
__device__ inline float bf2f(short s) {
  union { unsigned u; float f; } v; v.u = ((unsigned)(unsigned short)s) << 16;
  return v.f;
}
__device__ inline float relu_(float x) { return fmaxf(x, 0.0f); }

// ---------------------------------------------------------------------------
// prep: x1 -> bf16 (float4-wise), x2 -> bf16, W1 -> Wt1 (bf16, transposed),
//       W2 -> Wt2, zero stats. One kernel, region-partitioned flat index.
// ---------------------------------------------------------------------------
#define SEG0 2097152              // x1 in float4 units (8388608/4)
#define SEG1 1048576              // x2 in float4 units (4194304/4)
#define SEG2 65536                // W1 scalars
#define SEG3 131072               // W2 scalars
#define SEG4 1024                 // stats zeros
#define PREP_THREADS (SEG0 + SEG1 + SEG2 + SEG3 + SEG4)   // 3343360 = 256*13060

__global__ __launch_bounds__(256) void prep(
    const float* __restrict__ x1, const float* __restrict__ x2,
    const float* __restrict__ W1, const float* __restrict__ W2,
    short* __restrict__ x1b, short* __restrict__ x2b,
    short* __restrict__ Wt1, short* __restrict__ Wt2,
    float* __restrict__ stats)
{
  int i = blockIdx.x * 256 + threadIdx.x;
  if (i < SEG0) {
    float4 v = ((const float4*)x1)[i];
    short4 s = { f2bf(v.x), f2bf(v.y), f2bf(v.z), f2bf(v.w) };
    ((short4*)x1b)[i] = s;
  } else if (i < SEG0 + SEG1) {
    int k = i - SEG0;
    float4 v = ((const float4*)x2)[k];
    short4 s = { f2bf(v.x), f2bf(v.y), f2bf(v.z), f2bf(v.w) };
    ((short4*)x2b)[k] = s;
  } else if (i < SEG0 + SEG1 + SEG2) {
    int k = i - (SEG0 + SEG1);
    Wt1[(size_t)(k & 255) * COUT + (k >> 8)] = f2bf(W1[k]);
  } else if (i < SEG0 + SEG1 + SEG2 + SEG3) {
    int k = i - (SEG0 + SEG1 + SEG2);
    Wt2[(size_t)(k & 255) * CIN + (k >> 8)] = f2bf(W2[k]);
  } else {
    stats[i - (SEG0 + SEG1 + SEG2 + SEG3)] = 0.0f;
  }
}

// ---------------------------------------------------------------------------
// GEMM: Y[M][256](bf16) = Xb[M][K](bf16) @ Wt^T(bf16) + bias
// Tile BM=64 x BN=128 x BK=64. 256 threads = 4 waves; wave does 32x64.
// ---------------------------------------------------------------------------
#define BM 64
#define BN 128
#define BK 64

__global__ __launch_bounds__(256) void gemm_bias(
    const short* __restrict__ Xb, const short* __restrict__ Wt,
    const float* __restrict__ bias, short* __restrict__ Y,
    int M, int K)
{
  __shared__ __align__(16) short As[BM][BK + 8];   // 64 x 72 shorts
  __shared__ __align__(16) short Bs[BN][BK + 8];   // 128 x 72 shorts (Wt rows)

  const int bm = blockIdx.x * BM;
  const int bn = blockIdx.y * BN;
  const int tid = threadIdx.x;
  const int lane = tid & 63;
  const int wave = tid >> 6;
  const int wm = (wave & 1) * 32;
  const int wn = (wave >> 1) * 64;

  f32x4 acc[2][4];
  for (int i = 0; i < 2; i++)
    for (int j = 0; j < 4; j++)
      for (int e = 0; e < 4; e++) acc[i][j][e] = 0.0f;

  const int sr = tid >> 3;          // 0..31
  const int sk = (tid & 7) * 8;     // 0..56

  for (int k0 = 0; k0 < K; k0 += BK) {
    #pragma unroll
    for (int r = sr; r < BM; r += 32) {
      *(bf16x8*)&As[r][sk] = *(const bf16x8*)&Xb[(size_t)(bm + r) * K + k0 + sk];
    }
    #pragma unroll
    for (int r = sr; r < BN; r += 32) {
      *(bf16x8*)&Bs[r][sk] = *(const bf16x8*)&Wt[(size_t)(bn + r) * K + k0 + sk];
    }
    __syncthreads();

    const int fr = lane & 15;
    const int kq = (lane >> 4) * 8;
    #pragma unroll
    for (int ks = 0; ks < BK; ks += 32) {
      bf16x8 a0 = *(const bf16x8*)&As[wm + fr][ks + kq];
      bf16x8 a1 = *(const bf16x8*)&As[wm + 16 + fr][ks + kq];
      bf16x8 b0 = *(const bf16x8*)&Bs[wn + fr][ks + kq];
      bf16x8 b1 = *(const bf16x8*)&Bs[wn + 16 + fr][ks + kq];
      bf16x8 b2 = *(const bf16x8*)&Bs[wn + 32 + fr][ks + kq];
      bf16x8 b3 = *(const bf16x8*)&Bs[wn + 48 + fr][ks + kq];
      acc[0][0] = __builtin_amdgcn_mfma_f32_16x16x32_bf16(a0, b0, acc[0][0], 0, 0, 0);
      acc[0][1] = __builtin_amdgcn_mfma_f32_16x16x32_bf16(a0, b1, acc[0][1], 0, 0, 0);
      acc[0][2] = __builtin_amdgcn_mfma_f32_16x16x32_bf16(a0, b2, acc[0][2], 0, 0, 0);
      acc[0][3] = __builtin_amdgcn_mfma_f32_16x16x32_bf16(a0, b3, acc[0][3], 0, 0, 0);
      acc[1][0] = __builtin_amdgcn_mfma_f32_16x16x32_bf16(a1, b0, acc[1][0], 0, 0, 0);
      acc[1][1] = __builtin_amdgcn_mfma_f32_16x16x32_bf16(a1, b1, acc[1][1], 0, 0, 0);
      acc[1][2] = __builtin_amdgcn_mfma_f32_16x16x32_bf16(a1, b2, acc[1][2], 0, 0, 0);
      acc[1][3] = __builtin_amdgcn_mfma_f32_16x16x32_bf16(a1, b3, acc[1][3], 0, 0, 0);
    }
    __syncthreads();
  }

  // C/D: col = lane&15, row = (lane>>4)*4 + j
  const int col = lane & 15;
  const int rq = (lane >> 4) * 4;
  #pragma unroll
  for (int mi = 0; mi < 2; mi++) {
    #pragma unroll
    for (int ni = 0; ni < 4; ni++) {
      const int gm = bm + wm + mi * 16 + rq;
      const int gn = bn + wn + ni * 16 + col;
      const float bb = bias[gn];
      #pragma unroll
      for (int j = 0; j < 4; j++) {
        Y[(size_t)(gm + j) * 256 + gn] = f2bf(acc[mi][ni][j] + bb);
      }
    }
  }
}

// ---------------------------------------------------------------------------
// Per-channel sum / sumsq over 32-row slabs of Y[M][256] (bf16)
// ---------------------------------------------------------------------------
__global__ __launch_bounds__(256) void col_stats(
    const short* __restrict__ Y, float* __restrict__ sums)
{
  const int c = threadIdx.x;
  const int m0 = blockIdx.x * 32;
  float s = 0.0f, s2 = 0.0f;
  #pragma unroll 8
  for (int m = m0; m < m0 + 32; m++) {
    float v = bf2f(Y[(size_t)m * 256 + c]);
    s += v;
    s2 += v * v;
  }
  atomicAdd(&sums[c], s);
  atomicAdd(&sums[256 + c], s2);
}

__global__ __launch_bounds__(512) void finalize_both(
    const float* __restrict__ stats, const float* __restrict__ gamma1,
    const float* __restrict__ beta1, const float* __restrict__ gamma2,
    const float* __restrict__ beta2, float* __restrict__ ss)
{
  const int t = threadIdx.x;
  const int c = t & 255;
  const float* sums = (t < 256) ? stats : stats + 512;
  const float* gm = (t < 256) ? gamma1 : gamma2;
  const float* bt = (t < 256) ? beta1 : beta2;
  float* o = (t < 256) ? ss : ss + 512;
  const float invM = (t < 256) ? (1.0f / (B_ * N1_)) : (1.0f / (B_ * N2_));
  float mean = sums[c] * invM;
  float var = sums[256 + c] * invM - mean * mean;
  float sc = gm[c] * rsqrtf(var + 1e-5f);
  o[c] = sc;
  o[256 + c] = bt[c] - mean * sc;
}

// ---------------------------------------------------------------------------
// 3-NN: 8 threads/query, 32 queries/block. s1 folded out of the ranking
// (per-query constant), distance = 3 FMA; unrolled immediate-offset LDS reads.
// ---------------------------------------------------------------------------
#define INS(d, j)                                                   \
  { bool lt0 = (d) < d0, lt1 = (d) < d1, lt2 = (d) < d2;            \
    d2 = lt1 ? d1 : (lt2 ? (d) : d2); i2 = lt1 ? i1 : (lt2 ? (j) : i2); \
    d1 = lt0 ? d0 : (lt1 ? (d) : d1); i1 = lt0 ? i0 : (lt1 ? (j) : i1); \
    d0 = lt0 ? (d) : d0;              i0 = lt0 ? (j) : i0; }

__global__ __launch_bounds__(256) void knn_weights(
    const float* __restrict__ p1, const float* __restrict__ p2,
    float* __restrict__ wgt, int* __restrict__ idx)
{
  __shared__ float4 sp2[N2_];   // 32 KB: x,y,z,|p2|^2
  const int b = blockIdx.y;
  const float* P2 = p2 + (size_t)b * N2_ * 3;
  for (int j = threadIdx.x; j < N2_; j += 256) {
    float x = P2[j * 3 + 0], y = P2[j * 3 + 1], z = P2[j * 3 + 2];
    sp2[j] = make_float4(x, y, z, x * x + y * y + z * z);
  }
  __syncthreads();

  const int sub = threadIdx.x & 7;
  const int q = blockIdx.x * 32 + (threadIdx.x >> 3);
  const float* P1 = p1 + ((size_t)b * N1_ + q) * 3;
  const float x = P1[0], y = P1[1], z = P1[2];
  const float s1 = x * x + y * y + z * z;   // re-added at the weight step only
  const float nx = -2.0f * x, ny = -2.0f * y, nz = -2.0f * z;

  float d0 = 1e30f, d1 = 1e30f, d2 = 1e30f;
  int i0 = 0, i1 = 0, i2 = 0;
  const float4* base = &sp2[sub];
  int jb = sub;
  for (int t = 0; t < 32; t++) {
    #pragma unroll
    for (int u = 0; u < 8; u++) {
      float4 qq = base[u * 8];           // ds_read_b128, immediate offset u*128
      float d = fmaf(nx, qq.x, fmaf(ny, qq.y, fmaf(nz, qq.z, qq.w)));
      INS(d, jb + u * 8);
    }
    base += 64;
    jb += 64;
  }

  #pragma unroll
  for (int m = 1; m < 8; m <<= 1) {
    float e0 = __shfl_xor(d0, m), e1 = __shfl_xor(d1, m), e2 = __shfl_xor(d2, m);
    int j0 = __shfl_xor(i0, m), j1 = __shfl_xor(i1, m), j2 = __shfl_xor(i2, m);
    INS(e0, j0); INS(e1, j1); INS(e2, j2);
  }

  if (sub == 0) {
    float r0 = 1.0f / (d0 + s1 + 1e-8f);
    float r1 = 1.0f / (d1 + s1 + 1e-8f);
    float r2 = 1.0f / (d2 + s1 + 1e-8f);
    float rs = 1.0f / (r0 + r1 + r2);
    size_t o = ((size_t)b * N1_ + q) * 3;
    wgt[o + 0] = r0 * rs; wgt[o + 1] = r1 * rs; wgt[o + 2] = r2 * rs;
    idx[o + 0] = i0;      idx[o + 1] = i1;      idx[o + 2] = i2;
  }
}

// ---------------------------------------------------------------------------
// out = sum_k w_k * relu(bn2(y2[idx_k])) + relu(bn1(y1)); y1/y2 bf16
// ---------------------------------------------------------------------------
__global__ __launch_bounds__(256) void final_out(
    const short* __restrict__ y1, const short* __restrict__ y2,
    const float* __restrict__ ss1, const float* __restrict__ ss2,
    const float* __restrict__ wgt, const int* __restrict__ idx,
    float* __restrict__ out)
{
  const int r = blockIdx.x * 4 + (threadIdx.x >> 6);
  const int lane = threadIdx.x & 63;
  const int b = r >> 13;
  const size_t wo = (size_t)r * 3;
  const float w0 = wgt[wo], w1 = wgt[wo + 1], w2 = wgt[wo + 2];
  const int i0 = idx[wo], i1 = idx[wo + 1], i2 = idx[wo + 2];

  const short* g0 = y2 + ((size_t)b * N2_ + i0) * 256;
  const short* g1 = y2 + ((size_t)b * N2_ + i1) * 256;
  const short* g2 = y2 + ((size_t)b * N2_ + i2) * 256;
  const int c = lane * 4;

  short4 s0 = *(const short4*)&g0[c];
  short4 s1 = *(const short4*)&g1[c];
  short4 s2 = *(const short4*)&g2[c];
  short4 sv = *(const short4*)&y1[(size_t)r * 256 + c];
  float4 sc2 = *(const float4*)&ss2[c];
  float4 sh2 = *(const float4*)&ss2[256 + c];
  float4 sc1 = *(const float4*)&ss1[c];
  float4 sh1 = *(const float4*)&ss1[256 + c];

  float4 o;
  o.x = w0 * relu_(bf2f(s0.x) * sc2.x + sh2.x) + w1 * relu_(bf2f(s1.x) * sc2.x + sh2.x)
      + w2 * relu_(bf2f(s2.x) * sc2.x + sh2.x) + relu_(bf2f(sv.x) * sc1.x + sh1.x);
  o.y = w0 * relu_(bf2f(s0.y) * sc2.y + sh2.y) + w1 * relu_(bf2f(s1.y) * sc2.y + sh2.y)
      + w2 * relu_(bf2f(s2.y) * sc2.y + sh2.y) + relu_(bf2f(sv.y) * sc1.y + sh1.y);
  o.z = w0 * relu_(bf2f(s0.z) * sc2.z + sh2.z) + w1 * relu_(bf2f(s1.z) * sc2.z + sh2.z)
      + w2 * relu_(bf2f(s2.z) * sc2.z + sh2.z) + relu_(bf2f(sv.z) * sc1.z + sh1.z);
  o.w = w0 * relu_(bf2f(s0.w) * sc2.w + sh2.w) + w1 * relu_(bf2f(s1.w) * sc2.w + sh2.w)
      + w2 * relu_(bf2f(s2.w) * sc2.w + sh2.w) + relu_(bf2f(sv.w) * sc1.w + sh1.w);

  *(float4*)&out[(size_t)r * 256 + c] = o;
}

// ---------------------------------------------------------------------------
extern "C" void kernel_launch(void* const* d_in, const int* in_sizes, int n_in,
                              void* d_out, int out_size, void* d_ws, size_t ws_size,
                              hipStream_t stream)
{
  const float* p1  = (const float*)d_in[0];
  const float* x1  = (const float*)d_in[1];
  const float* p2  = (const float*)d_in[2];
  const float* x2  = (const float*)d_in[3];
  const float* W1  = (const float*)d_in[4];
  const float* b1  = (const float*)d_in[5];
  const float* g1  = (const float*)d_in[6];
  const float* be1 = (const float*)d_in[7];
  const float* W2  = (const float*)d_in[8];
  const float* b2  = (const float*)d_in[9];
  const float* g2  = (const float*)d_in[10];
  const float* be2 = (const float*)d_in[11];
  float* out = (float*)d_out;
  char* ws = (char*)d_ws;

  // workspace layout (bytes), total ~48 MB
  short* y1    = (short*)(ws + 0);            // 32768*256*2 = 16777216
  short* y2    = (short*)(ws + 16777216);     // 8192*256*2  =  4194304
  short* x1b   = (short*)(ws + 20971520);     // 32768*256*2 = 16777216
  short* x2b   = (short*)(ws + 37748736);     // 8192*512*2  =  8388608
  short* Wt1   = (short*)(ws + 46137344);     // 256*256*2   =   131072
  short* Wt2   = (short*)(ws + 46268416);     // 512*256*2   =   262144
  float* stats = (float*)(ws + 46530560);     // 1024 floats
  float* ss    = (float*)(ws + 46534656);     // 1024 floats
  float* wgt   = (float*)(ws + 46538752);     // 32768*3 floats = 393216
  int*   idx   = (int*)  (ws + 46931968);     // 32768*3 ints   = 393216

  prep<<<PREP_THREADS / 256, 256, 0, stream>>>(x1, x2, W1, W2, x1b, x2b, Wt1, Wt2, stats);

  knn_weights<<<dim3(N1_ / 32, B_), 256, 0, stream>>>(p1, p2, wgt, idx);

  gemm_bias<<<dim3((B_ * N2_) / BM, COUT / BN), 256, 0, stream>>>(x2b, Wt2, b2, y2, B_ * N2_, CIN);
  gemm_bias<<<dim3((B_ * N1_) / BM, COUT / BN), 256, 0, stream>>>(x1b, Wt1, b1, y1, B_ * N1_, COUT);

  col_stats<<<(B_ * N1_) / 32, 256, 0, stream>>>(y1, stats);
  col_stats<<<(B_ * N2_) / 32, 256, 0, stream>>>(y2, stats + 512);

  finalize_both<<<1, 512, 0, stream>>>(stats, g1, be1, g2, be2, ss);

  final_out<<<(B_ * N1_) / 4, 256, 0, stream>>>(y1, y2, ss, ss + 512, wgt, idx, out);
}

// Round 4
// 202.222 us; speedup vs baseline: 2.0194x; 1.1528x over previous
//
#include <hip/hip_runtime.h>

#define B_   4
#define N1_  8192
#define N2_  2048
#define CIN  512
#define COUT 256

typedef __attribute__((ext_vector_type(8))) short bf16x8;
typedef __attribute__((ext_vector_type(4))) float f32x4;

__device__ inline short f2bf(float f) {
  union { float f; unsigned u; } v; v.f = f;
  unsigned r = v.u + 0x7fffu + ((v.u >> 16) & 1u);
  return (short)(r >> 16);
}
__device__ inline float bf2f(short s) {
  union { unsigned u; float f; } v; v.u = ((unsigned)(unsigned short)s) << 16;
  return v.f;
}
__device__ inline float relu_(float x) { return fmaxf(x, 0.0f); }

// ---------------------------------------------------------------------------
// Launch 1: blocks [0,1024) = knn (VALU-bound), [1024,1796) = W transposes +
// stats zeroing (memory-bound, tiny) — overlapped in one dispatch.
// ---------------------------------------------------------------------------
#define INS(d, j)                                                   \
  { bool lt0 = (d) < d0, lt1 = (d) < d1, lt2 = (d) < d2;            \
    d2 = lt1 ? d1 : (lt2 ? (d) : d2); i2 = lt1 ? i1 : (lt2 ? (j) : i2); \
    d1 = lt0 ? d0 : (lt1 ? (d) : d1); i1 = lt0 ? i0 : (lt1 ? (j) : i1); \
    d0 = lt0 ? (d) : d0;              i0 = lt0 ? (j) : i0; }

__global__ __launch_bounds__(256) void knn_prep(
    const float* __restrict__ p1, const float* __restrict__ p2,
    const float* __restrict__ W1, const float* __restrict__ W2,
    float* __restrict__ wgt, int* __restrict__ idx,
    short* __restrict__ Wt1, short* __restrict__ Wt2,
    float* __restrict__ stats)
{
  __shared__ float4 sp2[N2_];   // 32 KB (only knn blocks touch it)
  const int bid = blockIdx.x;
  const int tid = threadIdx.x;

  if (bid >= 1024) {            // ---- prep region ----
    const int w = bid - 1024;
    if (w < 256) {
      int k = w * 256 + tid;    // W1: [256][256] -> Wt1 [256][256]^T
      Wt1[(size_t)(k & 255) * COUT + (k >> 8)] = f2bf(W1[k]);
    } else if (w < 768) {
      int k = (w - 256) * 256 + tid;   // W2: [512][256] -> Wt2 [256][512]
      Wt2[(size_t)(k & 255) * CIN + (k >> 8)] = f2bf(W2[k]);
    } else {
      stats[(w - 768) * 256 + tid] = 0.0f;
    }
    return;
  }

  // ---- knn region: 8 threads/query, 32 queries/block ----
  const int b = bid & 3;
  const int qg = bid >> 2;      // 0..255
  const float* P2 = p2 + (size_t)b * N2_ * 3;
  for (int j = tid; j < N2_; j += 256) {
    float x = P2[j * 3 + 0], y = P2[j * 3 + 1], z = P2[j * 3 + 2];
    sp2[j] = make_float4(x, y, z, x * x + y * y + z * z);
  }
  __syncthreads();

  const int sub = tid & 7;
  const int q = qg * 32 + (tid >> 3);
  const float* P1 = p1 + ((size_t)b * N1_ + q) * 3;
  const float x = P1[0], y = P1[1], z = P1[2];
  const float s1 = x * x + y * y + z * z;   // re-added only at the weight step
  const float nx = -2.0f * x, ny = -2.0f * y, nz = -2.0f * z;

  float d0 = 1e30f, d1 = 1e30f, d2 = 1e30f;
  int i0 = 0, i1 = 0, i2 = 0;
  const float4* base = &sp2[sub];
  int jb = sub;
  for (int t = 0; t < 32; t++) {
    #pragma unroll
    for (int u = 0; u < 8; u++) {
      float4 qq = base[u * 8];           // ds_read_b128, immediate offset
      float d = fmaf(nx, qq.x, fmaf(ny, qq.y, fmaf(nz, qq.z, qq.w)));
      INS(d, jb + u * 8);
    }
    base += 64;
    jb += 64;
  }

  #pragma unroll
  for (int m = 1; m < 8; m <<= 1) {
    float e0 = __shfl_xor(d0, m), e1 = __shfl_xor(d1, m), e2 = __shfl_xor(d2, m);
    int j0 = __shfl_xor(i0, m), j1 = __shfl_xor(i1, m), j2 = __shfl_xor(i2, m);
    INS(e0, j0); INS(e1, j1); INS(e2, j2);
  }

  if (sub == 0) {
    float r0 = 1.0f / (d0 + s1 + 1e-8f);
    float r1 = 1.0f / (d1 + s1 + 1e-8f);
    float r2 = 1.0f / (d2 + s1 + 1e-8f);
    float rs = 1.0f / (r0 + r1 + r2);
    size_t o = ((size_t)b * N1_ + q) * 3;
    wgt[o + 0] = r0 * rs; wgt[o + 1] = r1 * rs; wgt[o + 2] = r2 * rs;
    idx[o + 0] = i0;      idx[o + 1] = i1;      idx[o + 2] = i2;
  }
}

// ---------------------------------------------------------------------------
// Launch 2: both GEMMs in one grid. Y = X(fp32)@Wt^T(bf16) + bias, bf16 out,
// with per-channel sum/sumsq fused into the epilogue (atomicAdd into stats).
// Tile BM=64 x BN=128 x BK=64; blocks [0,256) = gemm2, [256,1280) = gemm1.
// ---------------------------------------------------------------------------
#define BM 64
#define BN 128
#define BK 64

__global__ __launch_bounds__(256) void gemm_fused(
    const float* __restrict__ x1, const float* __restrict__ x2,
    const short* __restrict__ Wt1, const short* __restrict__ Wt2,
    const float* __restrict__ bias1, const float* __restrict__ bias2,
    short* __restrict__ y1, short* __restrict__ y2,
    float* __restrict__ stats)
{
  __shared__ __align__(16) short As[BM][BK + 8];
  __shared__ __align__(16) short Bs[BN][BK + 8];

  const int bid = blockIdx.x;
  const float* X; const short* Wt; const float* bias; short* Y; float* st;
  int K, mb, nb;
  if (bid < 256) {
    X = x2; Wt = Wt2; bias = bias2; Y = y2; st = stats + 512; K = CIN;
    mb = bid >> 1; nb = bid & 1;
  } else {
    const int t = bid - 256;
    X = x1; Wt = Wt1; bias = bias1; Y = y1; st = stats; K = COUT;
    mb = t >> 1; nb = t & 1;
  }
  const int bm = mb * BM;
  const int bn = nb * BN;

  const int tid = threadIdx.x;
  const int lane = tid & 63;
  const int wave = tid >> 6;
  const int wm = (wave & 1) * 32;
  const int wn = (wave >> 1) * 64;

  f32x4 acc[2][4];
  for (int i = 0; i < 2; i++)
    for (int j = 0; j < 4; j++)
      for (int e = 0; e < 4; e++) acc[i][j][e] = 0.0f;

  const int ar = tid >> 4;          // A: 16 threads/row, float4 each
  const int ak = (tid & 15) * 4;
  const int br = tid >> 3;          // B: 8 threads/row, bf16x8 each
  const int bk = (tid & 7) * 8;

  for (int k0 = 0; k0 < K; k0 += BK) {
    #pragma unroll
    for (int r = ar; r < BM; r += 16) {
      float4 v = *(const float4*)&X[(size_t)(bm + r) * K + k0 + ak];
      short4 s = { f2bf(v.x), f2bf(v.y), f2bf(v.z), f2bf(v.w) };
      *(short4*)&As[r][ak] = s;
    }
    #pragma unroll
    for (int r = br; r < BN; r += 32) {
      *(bf16x8*)&Bs[r][bk] = *(const bf16x8*)&Wt[(size_t)(bn + r) * K + k0 + bk];
    }
    __syncthreads();

    const int fr = lane & 15;
    const int kq = (lane >> 4) * 8;
    #pragma unroll
    for (int ks = 0; ks < BK; ks += 32) {
      bf16x8 a0 = *(const bf16x8*)&As[wm + fr][ks + kq];
      bf16x8 a1 = *(const bf16x8*)&As[wm + 16 + fr][ks + kq];
      bf16x8 b0 = *(const bf16x8*)&Bs[wn + fr][ks + kq];
      bf16x8 b1 = *(const bf16x8*)&Bs[wn + 16 + fr][ks + kq];
      bf16x8 b2 = *(const bf16x8*)&Bs[wn + 32 + fr][ks + kq];
      bf16x8 b3 = *(const bf16x8*)&Bs[wn + 48 + fr][ks + kq];
      acc[0][0] = __builtin_amdgcn_mfma_f32_16x16x32_bf16(a0, b0, acc[0][0], 0, 0, 0);
      acc[0][1] = __builtin_amdgcn_mfma_f32_16x16x32_bf16(a0, b1, acc[0][1], 0, 0, 0);
      acc[0][2] = __builtin_amdgcn_mfma_f32_16x16x32_bf16(a0, b2, acc[0][2], 0, 0, 0);
      acc[0][3] = __builtin_amdgcn_mfma_f32_16x16x32_bf16(a0, b3, acc[0][3], 0, 0, 0);
      acc[1][0] = __builtin_amdgcn_mfma_f32_16x16x32_bf16(a1, b0, acc[1][0], 0, 0, 0);
      acc[1][1] = __builtin_amdgcn_mfma_f32_16x16x32_bf16(a1, b1, acc[1][1], 0, 0, 0);
      acc[1][2] = __builtin_amdgcn_mfma_f32_16x16x32_bf16(a1, b2, acc[1][2], 0, 0, 0);
      acc[1][3] = __builtin_amdgcn_mfma_f32_16x16x32_bf16(a1, b3, acc[1][3], 0, 0, 0);
    }
    __syncthreads();
  }

  // Epilogue: write Y (bf16) and accumulate per-column sum/sumsq.
  // C/D: col = lane&15, row = (lane>>4)*4 + j
  const int col = lane & 15;
  const int rq = (lane >> 4) * 4;
  float cs[4], cs2[4];
  #pragma unroll
  for (int ni = 0; ni < 4; ni++) { cs[ni] = 0.0f; cs2[ni] = 0.0f; }

  #pragma unroll
  for (int mi = 0; mi < 2; mi++) {
    #pragma unroll
    for (int ni = 0; ni < 4; ni++) {
      const int gm = bm + wm + mi * 16 + rq;
      const int gn = bn + wn + ni * 16 + col;
      const float bb = bias[gn];
      #pragma unroll
      for (int j = 0; j < 4; j++) {
        float v = acc[mi][ni][j] + bb;
        Y[(size_t)(gm + j) * 256 + gn] = f2bf(v);
        cs[ni] += v;
        cs2[ni] += v * v;
      }
    }
  }
  // reduce over the 4 row-groups (lanes differing in bits 4,5 share a column)
  #pragma unroll
  for (int ni = 0; ni < 4; ni++) {
    cs[ni]  += __shfl_xor(cs[ni], 16);  cs[ni]  += __shfl_xor(cs[ni], 32);
    cs2[ni] += __shfl_xor(cs2[ni], 16); cs2[ni] += __shfl_xor(cs2[ni], 32);
  }
  if (lane < 16) {
    #pragma unroll
    for (int ni = 0; ni < 4; ni++) {
      const int gn = bn + wn + ni * 16 + col;
      atomicAdd(&st[gn], cs[ni]);
      atomicAdd(&st[256 + gn], cs2[ni]);
    }
  }
}

// ---------------------------------------------------------------------------
// Launch 3: out = sum_k w_k * relu(bn2(y2[idx_k])) + relu(bn1(y1)),
// with BN scale/shift computed inline from raw stats (all L2-hot broadcast).
// ---------------------------------------------------------------------------
__global__ __launch_bounds__(256) void final_out(
    const short* __restrict__ y1, const short* __restrict__ y2,
    const float* __restrict__ stats,
    const float* __restrict__ gamma1, const float* __restrict__ beta1,
    const float* __restrict__ gamma2, const float* __restrict__ beta2,
    const float* __restrict__ wgt, const int* __restrict__ idx,
    float* __restrict__ out)
{
  const int r = blockIdx.x * 4 + (threadIdx.x >> 6);
  const int lane = threadIdx.x & 63;
  const int b = r >> 13;
  const int c = lane * 4;

  // inline BN params for channels c..c+3 (both branches)
  const float invM1 = 1.0f / (B_ * N1_), invM2 = 1.0f / (B_ * N2_);
  float4 su1 = *(const float4*)&stats[c];
  float4 sq1 = *(const float4*)&stats[256 + c];
  float4 su2 = *(const float4*)&stats[512 + c];
  float4 sq2 = *(const float4*)&stats[768 + c];
  float4 gm1 = *(const float4*)&gamma1[c];
  float4 bt1 = *(const float4*)&beta1[c];
  float4 gm2 = *(const float4*)&gamma2[c];
  float4 bt2 = *(const float4*)&beta2[c];

  float4 sc1, sh1, sc2, sh2;
  {
    float m, v;
    m = su1.x * invM1; v = sq1.x * invM1 - m * m; sc1.x = gm1.x * rsqrtf(v + 1e-5f); sh1.x = bt1.x - m * sc1.x;
    m = su1.y * invM1; v = sq1.y * invM1 - m * m; sc1.y = gm1.y * rsqrtf(v + 1e-5f); sh1.y = bt1.y - m * sc1.y;
    m = su1.z * invM1; v = sq1.z * invM1 - m * m; sc1.z = gm1.z * rsqrtf(v + 1e-5f); sh1.z = bt1.z - m * sc1.z;
    m = su1.w * invM1; v = sq1.w * invM1 - m * m; sc1.w = gm1.w * rsqrtf(v + 1e-5f); sh1.w = bt1.w - m * sc1.w;
    m = su2.x * invM2; v = sq2.x * invM2 - m * m; sc2.x = gm2.x * rsqrtf(v + 1e-5f); sh2.x = bt2.x - m * sc2.x;
    m = su2.y * invM2; v = sq2.y * invM2 - m * m; sc2.y = gm2.y * rsqrtf(v + 1e-5f); sh2.y = bt2.y - m * sc2.y;
    m = su2.z * invM2; v = sq2.z * invM2 - m * m; sc2.z = gm2.z * rsqrtf(v + 1e-5f); sh2.z = bt2.z - m * sc2.z;
    m = su2.w * invM2; v = sq2.w * invM2 - m * m; sc2.w = gm2.w * rsqrtf(v + 1e-5f); sh2.w = bt2.w - m * sc2.w;
  }

  const size_t wo = (size_t)r * 3;
  const float w0 = wgt[wo], w1 = wgt[wo + 1], w2 = wgt[wo + 2];
  const int i0 = idx[wo], i1 = idx[wo + 1], i2 = idx[wo + 2];

  const short* g0 = y2 + ((size_t)b * N2_ + i0) * 256;
  const short* g1 = y2 + ((size_t)b * N2_ + i1) * 256;
  const short* g2 = y2 + ((size_t)b * N2_ + i2) * 256;

  short4 s0 = *(const short4*)&g0[c];
  short4 s1 = *(const short4*)&g1[c];
  short4 s2 = *(const short4*)&g2[c];
  short4 sv = *(const short4*)&y1[(size_t)r * 256 + c];

  float4 o;
  o.x = w0 * relu_(bf2f(s0.x) * sc2.x + sh2.x) + w1 * relu_(bf2f(s1.x) * sc2.x + sh2.x)
      + w2 * relu_(bf2f(s2.x) * sc2.x + sh2.x) + relu_(bf2f(sv.x) * sc1.x + sh1.x);
  o.y = w0 * relu_(bf2f(s0.y) * sc2.y + sh2.y) + w1 * relu_(bf2f(s1.y) * sc2.y + sh2.y)
      + w2 * relu_(bf2f(s2.y) * sc2.y + sh2.y) + relu_(bf2f(sv.y) * sc1.y + sh1.y);
  o.z = w0 * relu_(bf2f(s0.z) * sc2.z + sh2.z) + w1 * relu_(bf2f(s1.z) * sc2.z + sh2.z)
      + w2 * relu_(bf2f(s2.z) * sc2.z + sh2.z) + relu_(bf2f(sv.z) * sc1.z + sh1.z);
  o.w = w0 * relu_(bf2f(s0.w) * sc2.w + sh2.w) + w1 * relu_(bf2f(s1.w) * sc2.w + sh2.w)
      + w2 * relu_(bf2f(s2.w) * sc2.w + sh2.w) + relu_(bf2f(sv.w) * sc1.w + sh1.w);

  *(float4*)&out[(size_t)r * 256 + c] = o;
}

// ---------------------------------------------------------------------------
extern "C" void kernel_launch(void* const* d_in, const int* in_sizes, int n_in,
                              void* d_out, int out_size, void* d_ws, size_t ws_size,
                              hipStream_t stream)
{
  const float* p1  = (const float*)d_in[0];
  const float* x1  = (const float*)d_in[1];
  const float* p2  = (const float*)d_in[2];
  const float* x2  = (const float*)d_in[3];
  const float* W1  = (const float*)d_in[4];
  const float* b1  = (const float*)d_in[5];
  const float* g1  = (const float*)d_in[6];
  const float* be1 = (const float*)d_in[7];
  const float* W2  = (const float*)d_in[8];
  const float* b2  = (const float*)d_in[9];
  const float* g2  = (const float*)d_in[10];
  const float* be2 = (const float*)d_in[11];
  float* out = (float*)d_out;
  char* ws = (char*)d_ws;

  // workspace layout (bytes), total ~22.5 MB
  short* y1    = (short*)(ws + 0);            // 32768*256*2 = 16777216
  short* y2    = (short*)(ws + 16777216);     // 8192*256*2  =  4194304
  short* Wt1   = (short*)(ws + 20971520);     // 256*256*2   =   131072
  short* Wt2   = (short*)(ws + 21102592);     // 512*256*2   =   262144
  float* stats = (float*)(ws + 21364736);     // 1024 floats
  float* wgt   = (float*)(ws + 21368832);     // 32768*3 floats = 393216
  int*   idx   = (int*)  (ws + 21762048);     // 32768*3 ints   = 393216

  knn_prep<<<1796, 256, 0, stream>>>(p1, p2, W1, W2, wgt, idx, Wt1, Wt2, stats);

  gemm_fused<<<1280, 256, 0, stream>>>(x1, x2, Wt1, Wt2, b1, b2, y1, y2, stats);

  final_out<<<(B_ * N1_) / 4, 256, 0, stream>>>(
      y1, y2, stats, g1, be1, g2, be2, wgt, idx, out);
}

// Round 5
// 177.143 us; speedup vs baseline: 2.3053x; 1.1416x over previous
//
#include <hip/hip_runtime.h>
#include <stdint.h>

#define B_   4
#define N1_  8192
#define N2_  2048
#define CIN  512
#define COUT 256

typedef __attribute__((ext_vector_type(8))) short bf16x8;
typedef __attribute__((ext_vector_type(4))) float f32x4;

__device__ inline short f2bf(float f) {
  union { float f; unsigned u; } v; v.f = f;
  unsigned r = v.u + 0x7fffu + ((v.u >> 16) & 1u);
  return (short)(r >> 16);
}
__device__ inline float bf2f(short s) {
  union { unsigned u; float f; } v; v.u = ((unsigned)(unsigned short)s) << 16;
  return v.f;
}
__device__ inline float relu_(float x) { return fmaxf(x, 0.0f); }

// async global->LDS, 16B per lane; LDS dest must be wave-uniform base (+lane*16)
typedef const __attribute__((address_space(1))) unsigned int* gas_t;
typedef __attribute__((address_space(3))) unsigned int* las_t;
__device__ __forceinline__ void g2l16(const short* g, short* l) {
  __builtin_amdgcn_global_load_lds((gas_t)g, (las_t)l, 16, 0, 0);
}

// ---------------------------------------------------------------------------
// Launch 1 regions: [0,512) knn (64 queries/block, 2/thread-group),
// [512,768) W1^T, [768,1280) W2^T, [1280,1284) stats zero,
// [1284,9476) x1->bf16, [9476,13572) x2->bf16.
// knn is VALU-bound, cvt is HBM-bound -> they overlap inside one dispatch.
// ---------------------------------------------------------------------------
#define KNN_B  512
#define W1_B0  512
#define W2_B0  768
#define ST_B0  1280
#define CV1_B0 1284
#define CV2_B0 9476
#define TOT_B  13572

#define INS3(d, j, d0, d1, d2, i0, i1, i2)                                \
  { bool lt0 = (d) < d0, lt1 = (d) < d1, lt2 = (d) < d2;                  \
    d2 = lt1 ? d1 : (lt2 ? (d) : d2); i2 = lt1 ? i1 : (lt2 ? (j) : i2);   \
    d1 = lt0 ? d0 : (lt1 ? (d) : d1); i1 = lt0 ? i0 : (lt1 ? (j) : i1);   \
    d0 = lt0 ? (d) : d0;              i0 = lt0 ? (j) : i0; }

__global__ __launch_bounds__(256) void knn_prep(
    const float* __restrict__ p1, const float* __restrict__ p2,
    const float* __restrict__ W1, const float* __restrict__ W2,
    const float* __restrict__ x1, const float* __restrict__ x2,
    float* __restrict__ wgt, int* __restrict__ idx,
    short* __restrict__ Wt1, short* __restrict__ Wt2,
    short* __restrict__ x1b, short* __restrict__ x2b,
    float* __restrict__ stats)
{
  __shared__ float4 sp2[N2_];   // 32 KB (knn blocks only)
  const int bid = blockIdx.x;
  const int tid = threadIdx.x;

  if (bid >= KNN_B) {
    if (bid >= CV2_B0) {
      int i = (bid - CV2_B0) * 256 + tid;
      float4 v = ((const float4*)x2)[i];
      short4 s = { f2bf(v.x), f2bf(v.y), f2bf(v.z), f2bf(v.w) };
      ((short4*)x2b)[i] = s;
    } else if (bid >= CV1_B0) {
      int i = (bid - CV1_B0) * 256 + tid;
      float4 v = ((const float4*)x1)[i];
      short4 s = { f2bf(v.x), f2bf(v.y), f2bf(v.z), f2bf(v.w) };
      ((short4*)x1b)[i] = s;
    } else if (bid >= ST_B0) {
      stats[(bid - ST_B0) * 256 + tid] = 0.0f;
    } else if (bid >= W2_B0) {
      int k = (bid - W2_B0) * 256 + tid;     // over 512*256
      Wt2[(size_t)(k & 255) * CIN + (k >> 8)] = f2bf(W2[k]);
    } else {
      int k = (bid - W1_B0) * 256 + tid;     // over 256*256
      Wt1[(size_t)(k & 255) * COUT + (k >> 8)] = f2bf(W1[k]);
    }
    return;
  }

  // ---- knn: 8 threads/query, 2 queries/thread, 64 queries/block ----
  const int b = bid & 3;
  const int qg = bid >> 2;                   // 0..127
  const float* P2 = p2 + (size_t)b * N2_ * 3;
  for (int j = tid; j < N2_; j += 256) {
    float x = P2[j * 3 + 0], y = P2[j * 3 + 1], z = P2[j * 3 + 2];
    sp2[j] = make_float4(x, y, z, x * x + y * y + z * z);
  }
  __syncthreads();

  const int sub = tid & 7;
  const int q0 = qg * 64 + (tid >> 3);
  const int q1 = q0 + 32;
  const float* A0 = p1 + ((size_t)b * N1_ + q0) * 3;
  const float* A1 = p1 + ((size_t)b * N1_ + q1) * 3;
  const float ax = A0[0], ay = A0[1], az = A0[2];
  const float bx = A1[0], by = A1[1], bz = A1[2];
  const float sA = ax * ax + ay * ay + az * az;
  const float sB = bx * bx + by * by + bz * bz;
  const float nax = -2.0f * ax, nay = -2.0f * ay, naz = -2.0f * az;
  const float nbx = -2.0f * bx, nby = -2.0f * by, nbz = -2.0f * bz;

  float a0 = 1e30f, a1 = 1e30f, a2 = 1e30f; int ia0 = 0, ia1 = 0, ia2 = 0;
  float b0 = 1e30f, b1 = 1e30f, b2 = 1e30f; int ib0 = 0, ib1 = 0, ib2 = 0;

  const float4* base = &sp2[sub];
  int jb = sub;
  for (int t = 0; t < 32; t++) {
    #pragma unroll
    for (int u = 0; u < 8; u++) {
      float4 qq = base[u * 8];               // ds_read_b128, imm offset
      float dA = fmaf(nax, qq.x, fmaf(nay, qq.y, fmaf(naz, qq.z, qq.w)));
      float dB = fmaf(nbx, qq.x, fmaf(nby, qq.y, fmaf(nbz, qq.z, qq.w)));
      INS3(dA, jb + u * 8, a0, a1, a2, ia0, ia1, ia2);
      INS3(dB, jb + u * 8, b0, b1, b2, ib0, ib1, ib2);
    }
    base += 64;
    jb += 64;
  }

  #pragma unroll
  for (int m = 1; m < 8; m <<= 1) {
    float e0 = __shfl_xor(a0, m), e1 = __shfl_xor(a1, m), e2 = __shfl_xor(a2, m);
    int j0 = __shfl_xor(ia0, m), j1 = __shfl_xor(ia1, m), j2 = __shfl_xor(ia2, m);
    INS3(e0, j0, a0, a1, a2, ia0, ia1, ia2);
    INS3(e1, j1, a0, a1, a2, ia0, ia1, ia2);
    INS3(e2, j2, a0, a1, a2, ia0, ia1, ia2);
    float f0 = __shfl_xor(b0, m), f1 = __shfl_xor(b1, m), f2 = __shfl_xor(b2, m);
    int k0 = __shfl_xor(ib0, m), k1 = __shfl_xor(ib1, m), k2 = __shfl_xor(ib2, m);
    INS3(f0, k0, b0, b1, b2, ib0, ib1, ib2);
    INS3(f1, k1, b0, b1, b2, ib0, ib1, ib2);
    INS3(f2, k2, b0, b1, b2, ib0, ib1, ib2);
  }

  if (sub == 0) {
    {
      float r0 = 1.0f / (a0 + sA + 1e-8f);
      float r1 = 1.0f / (a1 + sA + 1e-8f);
      float r2 = 1.0f / (a2 + sA + 1e-8f);
      float rs = 1.0f / (r0 + r1 + r2);
      size_t o = ((size_t)b * N1_ + q0) * 3;
      wgt[o + 0] = r0 * rs; wgt[o + 1] = r1 * rs; wgt[o + 2] = r2 * rs;
      idx[o + 0] = ia0;     idx[o + 1] = ia1;     idx[o + 2] = ia2;
    }
    {
      float r0 = 1.0f / (b0 + sB + 1e-8f);
      float r1 = 1.0f / (b1 + sB + 1e-8f);
      float r2 = 1.0f / (b2 + sB + 1e-8f);
      float rs = 1.0f / (r0 + r1 + r2);
      size_t o = ((size_t)b * N1_ + q1) * 3;
      wgt[o + 0] = r0 * rs; wgt[o + 1] = r1 * rs; wgt[o + 2] = r2 * rs;
      idx[o + 0] = ib0;     idx[o + 1] = ib1;     idx[o + 2] = ib2;
    }
  }
}

// ---------------------------------------------------------------------------
// Launch 2: both GEMMs, m97-style. Y = Xb(bf16) @ Wt^T(bf16) + bias -> bf16,
// stats fused. Tile 128x128x64, global_load_lds(16B) staging, XOR-swizzled
// LDS pieces (swizzle applied on global address; LDS placement is HW-fixed).
// Blocks [0,128) = gemm2 (K=512, longer), [128,640) = gemm1 (K=256).
// ---------------------------------------------------------------------------
#define GBM 128
#define GBN 128
#define GBK 64

__global__ __launch_bounds__(256) void gemm_fused(
    const short* __restrict__ x1b, const short* __restrict__ x2b,
    const short* __restrict__ Wt1, const short* __restrict__ Wt2,
    const float* __restrict__ bias1, const float* __restrict__ bias2,
    short* __restrict__ y1, short* __restrict__ y2,
    float* __restrict__ stats)
{
  __shared__ __align__(16) short As[GBM * GBK];   // 16 KB, row-major [128][64]
  __shared__ __align__(16) short Bs[GBN * GBK];   // 16 KB

  const int bid = blockIdx.x;
  const short* X; const short* Wt; const float* bias; short* Y; float* st;
  int K, mb, nb;
  if (bid < 128) {
    X = x2b; Wt = Wt2; bias = bias2; Y = y2; st = stats + 512; K = CIN;
    mb = bid >> 1; nb = bid & 1;
  } else {
    const int t = bid - 128;
    X = x1b; Wt = Wt1; bias = bias1; Y = y1; st = stats; K = COUT;
    mb = t >> 1; nb = t & 1;
  }
  const int bm = mb * GBM;
  const int bn = nb * GBN;

  const int tid = threadIdx.x, lane = tid & 63, wave = tid >> 6;
  const int wm = (wave & 1) * 64, wn = (wave >> 1) * 64;

  f32x4 acc[4][4];
  #pragma unroll
  for (int i = 0; i < 4; i++)
    #pragma unroll
    for (int j = 0; j < 4; j++)
      #pragma unroll
      for (int e = 0; e < 4; e++) acc[i][j][e] = 0.0f;

  // staging: lane covers row (chunk*8 + lr), swizzled 16B piece lp
  const int lr = lane >> 3;                 // 0..7
  const int lp = (lane & 7) ^ lr;           // piece swizzle: phys p holds logical p^row7
  const int lk = lp * 8;                    // bf16 offset in row

  // fragment read addressing (reads must undo the swizzle)
  const int fr = lane & 15;
  const int quad = lane >> 4;               // 0..3
  const int pA0 = ((quad ^ (fr & 7)) * 16); // byte offset of ks=0 16B piece

  for (int k0 = 0; k0 < K; k0 += GBK) {
    #pragma unroll
    for (int i = 0; i < 4; i++) {
      const int crow = wave * 4 + i;        // chunk 0..15 (8 rows each)
      g2l16(X  + (size_t)(bm + crow * 8 + lr) * K + k0 + lk, As + crow * 512);
      g2l16(Wt + (size_t)(bn + crow * 8 + lr) * K + k0 + lk, Bs + crow * 512);
    }
    __syncthreads();   // compiler emits vmcnt(0) drain before barrier

    #pragma unroll
    for (int ks = 0; ks < 2; ks++) {
      const int xo = ks * 64;               // flips piece bit2 (ks=32 -> +4 pieces)
      bf16x8 af[4], bf[4];
      #pragma unroll
      for (int i = 0; i < 4; i++) {
        af[i] = *(const bf16x8*)((const char*)As + (wm + i * 16 + fr) * 128 + (pA0 ^ xo));
        bf[i] = *(const bf16x8*)((const char*)Bs + (wn + i * 16 + fr) * 128 + (pA0 ^ xo));
      }
      #pragma unroll
      for (int i = 0; i < 4; i++)
        #pragma unroll
        for (int j = 0; j < 4; j++)
          acc[i][j] = __builtin_amdgcn_mfma_f32_16x16x32_bf16(af[i], bf[j], acc[i][j], 0, 0, 0);
    }
    __syncthreads();
  }

  // Epilogue: bias, bf16 write, fused per-column sum/sumsq.
  // C/D: col = lane&15, row = quad*4 + j
  const int col = fr;
  const int rq = quad * 4;
  float cs[4], cs2[4];
  #pragma unroll
  for (int ni = 0; ni < 4; ni++) { cs[ni] = 0.0f; cs2[ni] = 0.0f; }

  #pragma unroll
  for (int mi = 0; mi < 4; mi++) {
    #pragma unroll
    for (int ni = 0; ni < 4; ni++) {
      const int gm = bm + wm + mi * 16 + rq;
      const int gn = bn + wn + ni * 16 + col;
      const float bb = bias[gn];
      #pragma unroll
      for (int j = 0; j < 4; j++) {
        float v = acc[mi][ni][j] + bb;
        Y[(size_t)(gm + j) * 256 + gn] = f2bf(v);
        cs[ni] += v;
        cs2[ni] += v * v;
      }
    }
  }
  #pragma unroll
  for (int ni = 0; ni < 4; ni++) {
    cs[ni]  += __shfl_xor(cs[ni], 16);  cs[ni]  += __shfl_xor(cs[ni], 32);
    cs2[ni] += __shfl_xor(cs2[ni], 16); cs2[ni] += __shfl_xor(cs2[ni], 32);
  }
  if (lane < 16) {
    #pragma unroll
    for (int ni = 0; ni < 4; ni++) {
      const int gn = bn + wn + ni * 16 + col;
      atomicAdd(&st[gn], cs[ni]);
      atomicAdd(&st[256 + gn], cs2[ni]);
    }
  }
}

// ---------------------------------------------------------------------------
// Launch 3: out = sum_k w_k * relu(bn2(y2[idx_k])) + relu(bn1(y1)),
// BN scale/shift computed inline from raw stats (L2-hot broadcast reads).
// ---------------------------------------------------------------------------
__global__ __launch_bounds__(256) void final_out(
    const short* __restrict__ y1, const short* __restrict__ y2,
    const float* __restrict__ stats,
    const float* __restrict__ gamma1, const float* __restrict__ beta1,
    const float* __restrict__ gamma2, const float* __restrict__ beta2,
    const float* __restrict__ wgt, const int* __restrict__ idx,
    float* __restrict__ out)
{
  const int r = blockIdx.x * 4 + (threadIdx.x >> 6);
  const int lane = threadIdx.x & 63;
  const int b = r >> 13;
  const int c = lane * 4;

  const float invM1 = 1.0f / (B_ * N1_), invM2 = 1.0f / (B_ * N2_);
  float4 su1 = *(const float4*)&stats[c];
  float4 sq1 = *(const float4*)&stats[256 + c];
  float4 su2 = *(const float4*)&stats[512 + c];
  float4 sq2 = *(const float4*)&stats[768 + c];
  float4 gm1 = *(const float4*)&gamma1[c];
  float4 bt1 = *(const float4*)&beta1[c];
  float4 gm2 = *(const float4*)&gamma2[c];
  float4 bt2 = *(const float4*)&beta2[c];

  float4 sc1, sh1, sc2, sh2;
  {
    float m, v;
    m = su1.x * invM1; v = sq1.x * invM1 - m * m; sc1.x = gm1.x * rsqrtf(v + 1e-5f); sh1.x = bt1.x - m * sc1.x;
    m = su1.y * invM1; v = sq1.y * invM1 - m * m; sc1.y = gm1.y * rsqrtf(v + 1e-5f); sh1.y = bt1.y - m * sc1.y;
    m = su1.z * invM1; v = sq1.z * invM1 - m * m; sc1.z = gm1.z * rsqrtf(v + 1e-5f); sh1.z = bt1.z - m * sc1.z;
    m = su1.w * invM1; v = sq1.w * invM1 - m * m; sc1.w = gm1.w * rsqrtf(v + 1e-5f); sh1.w = bt1.w - m * sc1.w;
    m = su2.x * invM2; v = sq2.x * invM2 - m * m; sc2.x = gm2.x * rsqrtf(v + 1e-5f); sh2.x = bt2.x - m * sc2.x;
    m = su2.y * invM2; v = sq2.y * invM2 - m * m; sc2.y = gm2.y * rsqrtf(v + 1e-5f); sh2.y = bt2.y - m * sc2.y;
    m = su2.z * invM2; v = sq2.z * invM2 - m * m; sc2.z = gm2.z * rsqrtf(v + 1e-5f); sh2.z = bt2.z - m * sc2.z;
    m = su2.w * invM2; v = sq2.w * invM2 - m * m; sc2.w = gm2.w * rsqrtf(v + 1e-5f); sh2.w = bt2.w - m * sc2.w;
  }

  const size_t wo = (size_t)r * 3;
  const float w0 = wgt[wo], w1 = wgt[wo + 1], w2 = wgt[wo + 2];
  const int i0 = idx[wo], i1 = idx[wo + 1], i2 = idx[wo + 2];

  const short* g0 = y2 + ((size_t)b * N2_ + i0) * 256;
  const short* g1 = y2 + ((size_t)b * N2_ + i1) * 256;
  const short* g2 = y2 + ((size_t)b * N2_ + i2) * 256;

  short4 s0 = *(const short4*)&g0[c];
  short4 s1 = *(const short4*)&g1[c];
  short4 s2 = *(const short4*)&g2[c];
  short4 sv = *(const short4*)&y1[(size_t)r * 256 + c];

  float4 o;
  o.x = w0 * relu_(bf2f(s0.x) * sc2.x + sh2.x) + w1 * relu_(bf2f(s1.x) * sc2.x + sh2.x)
      + w2 * relu_(bf2f(s2.x) * sc2.x + sh2.x) + relu_(bf2f(sv.x) * sc1.x + sh1.x);
  o.y = w0 * relu_(bf2f(s0.y) * sc2.y + sh2.y) + w1 * relu_(bf2f(s1.y) * sc2.y + sh2.y)
      + w2 * relu_(bf2f(s2.y) * sc2.y + sh2.y) + relu_(bf2f(sv.y) * sc1.y + sh1.y);
  o.z = w0 * relu_(bf2f(s0.z) * sc2.z + sh2.z) + w1 * relu_(bf2f(s1.z) * sc2.z + sh2.z)
      + w2 * relu_(bf2f(s2.z) * sc2.z + sh2.z) + relu_(bf2f(sv.z) * sc1.z + sh1.z);
  o.w = w0 * relu_(bf2f(s0.w) * sc2.w + sh2.w) + w1 * relu_(bf2f(s1.w) * sc2.w + sh2.w)
      + w2 * relu_(bf2f(s2.w) * sc2.w + sh2.w) + relu_(bf2f(sv.w) * sc1.w + sh1.w);

  *(float4*)&out[(size_t)r * 256 + c] = o;
}

// ---------------------------------------------------------------------------
extern "C" void kernel_launch(void* const* d_in, const int* in_sizes, int n_in,
                              void* d_out, int out_size, void* d_ws, size_t ws_size,
                              hipStream_t stream)
{
  const float* p1  = (const float*)d_in[0];
  const float* x1  = (const float*)d_in[1];
  const float* p2  = (const float*)d_in[2];
  const float* x2  = (const float*)d_in[3];
  const float* W1  = (const float*)d_in[4];
  const float* b1  = (const float*)d_in[5];
  const float* g1  = (const float*)d_in[6];
  const float* be1 = (const float*)d_in[7];
  const float* W2  = (const float*)d_in[8];
  const float* b2  = (const float*)d_in[9];
  const float* g2  = (const float*)d_in[10];
  const float* be2 = (const float*)d_in[11];
  float* out = (float*)d_out;
  char* ws = (char*)d_ws;

  // workspace layout (bytes), total ~47.3 MB
  short* y1    = (short*)(ws + 0);            // 32768*256*2 = 16777216
  short* y2    = (short*)(ws + 16777216);     // 8192*256*2  =  4194304
  short* x1b   = (short*)(ws + 20971520);     // 32768*256*2 = 16777216
  short* x2b   = (short*)(ws + 37748736);     // 8192*512*2  =  8388608
  short* Wt1   = (short*)(ws + 46137344);     // 256*256*2   =   131072
  short* Wt2   = (short*)(ws + 46268416);     // 512*256*2   =   262144
  float* stats = (float*)(ws + 46530560);     // 1024 floats
  float* wgt   = (float*)(ws + 46534656);     // 32768*3 floats
  int*   idx   = (int*)  (ws + 46927872);     // 32768*3 ints

  knn_prep<<<TOT_B, 256, 0, stream>>>(p1, p2, W1, W2, x1, x2,
                                      wgt, idx, Wt1, Wt2, x1b, x2b, stats);

  gemm_fused<<<640, 256, 0, stream>>>(x1b, x2b, Wt1, Wt2, b1, b2, y1, y2, stats);

  final_out<<<(B_ * N1_) / 4, 256, 0, stream>>>(
      y1, y2, stats, g1, be1, g2, be2, wgt, idx, out);
}